// Round 1
// baseline (802.173 us; speedup 1.0000x reference)
//
#include <hip/hip_runtime.h>
#include <math.h>

#define DDIM 1024
#define NH 16
#define HDIM 64
#define SCALE 0.125f
#define DLAM -0.1f
#define LNEPS 1e-5f

__device__ inline float dot4(float4 a, float4 b) {
    return fmaf(a.x, b.x, fmaf(a.y, b.y, fmaf(a.z, b.z, a.w * b.w)));
}

// K1: q[b,:] = query[b,:] @ Wq + bq
__global__ __launch_bounds__(256) void k_q(const float* __restrict__ query,
                                           const float* __restrict__ Wq,
                                           const float* __restrict__ bq,
                                           float* __restrict__ qout) {
    int b = blockIdx.x;
    __shared__ float qs[DDIM];
    for (int i = threadIdx.x; i < DDIM; i += 256) qs[i] = query[b * DDIM + i];
    __syncthreads();
    int t = threadIdx.x;
    float a0 = bq[t], a1 = bq[t + 256], a2 = bq[t + 512], a3 = bq[t + 768];
    for (int d = 0; d < DDIM; ++d) {
        float qv = qs[d];
        const float* wr = Wq + (size_t)d * DDIM;
        a0 = fmaf(qv, wr[t], a0);
        a1 = fmaf(qv, wr[t + 256], a1);
        a2 = fmaf(qv, wr[t + 512], a2);
        a3 = fmaf(qv, wr[t + 768], a3);
    }
    qout[b * DDIM + t] = a0;
    qout[b * DDIM + t + 256] = a1;
    qout[b * DDIM + t + 512] = a2;
    qout[b * DDIM + t + 768] = a3;
}

// K2: qp[b,h,d] = (1/8) * sum_j Wk[d, h*64+j] * q[b, h*64+j]
__global__ __launch_bounds__(256) void k_qp(const float* __restrict__ qin,
                                            const float* __restrict__ Wk,
                                            float* __restrict__ qp) {
    int b = blockIdx.x, dt = blockIdx.y;
    __shared__ float qs[DDIM];
    for (int i = threadIdx.x; i < DDIM; i += 256) qs[i] = qin[b * DDIM + i];
    __syncthreads();
    int h = threadIdx.x & 15, dl = threadIdx.x >> 4;
    int d = dt * 16 + dl;
    const float* wr = Wk + (size_t)d * DDIM + h * HDIM;
    const float* qh = qs + h * HDIM;
    float acc = 0.f;
#pragma unroll
    for (int j = 0; j < HDIM; ++j) acc = fmaf(wr[j], qh[j], acc);
    qp[((size_t)(b * NH + h)) * DDIM + d] = acc * SCALE;
}

// K2b: sb[b,h] = (1/8) * sum_j bk[h*64+j] * q[b, h*64+j]
__global__ __launch_bounds__(512) void k_sb(const float* __restrict__ qin,
                                            const float* __restrict__ bk,
                                            float* __restrict__ sb) {
    int idx = threadIdx.x;  // b*16 + h
    int b = idx >> 4, h = idx & 15;
    float acc = 0.f;
#pragma unroll
    for (int j = 0; j < HDIM; ++j)
        acc = fmaf(bk[h * HDIM + j], qin[b * DDIM + h * HDIM + j], acc);
    sb[idx] = acc * SCALE;
}

// K3: scores[b,h,n] = ctx[b,n,:].qp[b,h,:] + sb[b,h] + dist*lambda, masked
__global__ __launch_bounds__(256) void k_scores(const float* __restrict__ ctx,
                                                const float* __restrict__ qp,
                                                const float* __restrict__ sb,
                                                const float* __restrict__ dist,
                                                const int* __restrict__ mask,
                                                float* __restrict__ scores, int N) {
    int b = blockIdx.x, n0 = blockIdx.y * 64;
    int lane = threadIdx.x & 63, w = threadIdx.x >> 6;
    int h0 = w * 4;
    float4 qr[4][4];
#pragma unroll
    for (int hh = 0; hh < 4; ++hh) {
        const float4* p = reinterpret_cast<const float4*>(
            qp + ((size_t)(b * NH + h0 + hh)) * DDIM + lane * 16);
        qr[hh][0] = p[0]; qr[hh][1] = p[1]; qr[hh][2] = p[2]; qr[hh][3] = p[3];
    }
    float sbr[4];
#pragma unroll
    for (int hh = 0; hh < 4; ++hh) sbr[hh] = sb[b * NH + h0 + hh];

    for (int r = 0; r < 64; ++r) {
        int n = n0 + r;
        const float4* c = reinterpret_cast<const float4*>(
            ctx + ((size_t)b * N + n) * DDIM + lane * 16);
        float4 c0 = c[0], c1 = c[1], c2 = c[2], c3 = c[3];
        float p[4];
#pragma unroll
        for (int hh = 0; hh < 4; ++hh) {
            p[hh] = dot4(c0, qr[hh][0]) + dot4(c1, qr[hh][1]) +
                    dot4(c2, qr[hh][2]) + dot4(c3, qr[hh][3]);
        }
#pragma unroll
        for (int off = 32; off > 0; off >>= 1) {
#pragma unroll
            for (int hh = 0; hh < 4; ++hh) p[hh] += __shfl_xor(p[hh], off, 64);
        }
        if (lane == 0) {
            float dv = dist[(size_t)b * N + n] * DLAM;
            int mk = mask[(size_t)b * N + n];
#pragma unroll
            for (int hh = 0; hh < 4; ++hh) {
                float s = p[hh] + sbr[hh] + dv;
                if (mk == 0) s = -1e9f;
                scores[((size_t)(b * NH + h0 + hh)) * N + n] = s;
            }
        }
    }
}

// K4: in-place row softmax over N=4096 (16 elems/thread)
__global__ __launch_bounds__(256) void k_softmax(float* __restrict__ scores, int N) {
    int row = blockIdx.x;
    float* s = scores + (size_t)row * N;
    int t = threadIdx.x;
    __shared__ float red[4];
    float v[16];
    float mx = -3.4e38f;
#pragma unroll
    for (int i = 0; i < 16; ++i) {
        v[i] = s[t + i * 256];
        mx = fmaxf(mx, v[i]);
    }
#pragma unroll
    for (int off = 32; off > 0; off >>= 1) mx = fmaxf(mx, __shfl_xor(mx, off, 64));
    if ((t & 63) == 0) red[t >> 6] = mx;
    __syncthreads();
    mx = fmaxf(fmaxf(red[0], red[1]), fmaxf(red[2], red[3]));
    __syncthreads();
    float sum = 0.f;
#pragma unroll
    for (int i = 0; i < 16; ++i) {
        v[i] = __expf(v[i] - mx);
        sum += v[i];
    }
#pragma unroll
    for (int off = 32; off > 0; off >>= 1) sum += __shfl_xor(sum, off, 64);
    if ((t & 63) == 0) red[t >> 6] = sum;
    __syncthreads();
    sum = red[0] + red[1] + red[2] + red[3];
    float inv = 1.f / sum;
#pragma unroll
    for (int i = 0; i < 16; ++i) s[t + i * 256] = v[i] * inv;
}

// K5: partial weighted context sum over an n-split
// part[b,ns,h,d] = sum_{n in split} attn[b,h,n] * ctx[b,n,d]
__global__ __launch_bounds__(256) void k_wsum(const float* __restrict__ ctx,
                                              const float* __restrict__ attn,
                                              float* __restrict__ part, int N) {
    int b = blockIdx.x, dt = blockIdx.y, ns = blockIdx.z;
    int q4 = threadIdx.x & 63, hg = threadIdx.x >> 6;
    int d = dt * 256 + q4 * 4;
    int h0 = hg * 4;
    __shared__ float sm[NH][128];
    float4 acc[4];
#pragma unroll
    for (int hh = 0; hh < 4; ++hh) acc[hh] = make_float4(0.f, 0.f, 0.f, 0.f);
    int nchunk = N / 4;
    int nbase = ns * nchunk;
    for (int c0 = 0; c0 < nchunk; c0 += 128) {
        __syncthreads();
        for (int i = threadIdx.x; i < NH * 128; i += 256) {
            int h = i >> 7, nl = i & 127;
            sm[h][nl] = attn[((size_t)(b * NH + h)) * N + nbase + c0 + nl];
        }
        __syncthreads();
        const float4* cp = reinterpret_cast<const float4*>(
            ctx + ((size_t)b * N + nbase + c0) * DDIM + d);
        for (int nl = 0; nl < 128; ++nl) {
            float4 cv = *cp;
            cp += DDIM / 4;
#pragma unroll
            for (int hh = 0; hh < 4; ++hh) {
                float a = sm[h0 + hh][nl];
                acc[hh].x = fmaf(a, cv.x, acc[hh].x);
                acc[hh].y = fmaf(a, cv.y, acc[hh].y);
                acc[hh].z = fmaf(a, cv.z, acc[hh].z);
                acc[hh].w = fmaf(a, cv.w, acc[hh].w);
            }
        }
    }
#pragma unroll
    for (int hh = 0; hh < 4; ++hh) {
        float4* pp = reinterpret_cast<float4*>(
            part + (((size_t)(b * 4 + ns)) * NH + h0 + hh) * DDIM + d);
        *pp = acc[hh];
    }
}

// K6: reduce n-split partials
__global__ __launch_bounds__(256) void k_red(const float* __restrict__ part,
                                             float* __restrict__ ctxa) {
    int row = blockIdx.x;  // b*16 + h
    int b = row >> 4, h = row & 15;
    int t = threadIdx.x;
#pragma unroll
    for (int k = 0; k < 4; ++k) {
        int d = t + k * 256;
        float s = 0.f;
#pragma unroll
        for (int ns = 0; ns < 4; ++ns)
            s += part[(((size_t)(b * 4 + ns)) * NH + h) * DDIM + d];
        ctxa[(size_t)row * DDIM + d] = s;
    }
}

// K6b: oattn[b, h*64+j] = sum_d ctxa[b,h,d] * Wv[d, h*64+j] + bv
__global__ __launch_bounds__(256) void k_vproj(const float* __restrict__ ctxa,
                                               const float* __restrict__ Wv,
                                               const float* __restrict__ bv,
                                               float* __restrict__ oattn) {
    int b = blockIdx.x;
    int t = threadIdx.x;
    float acc[4];
    int hofk[4];
#pragma unroll
    for (int k = 0; k < 4; ++k) {
        int c = t + k * 256;
        acc[k] = bv[c];
        hofk[k] = c >> 6;
    }
    const float* cb = ctxa + (size_t)b * NH * DDIM;
    for (int d = 0; d < DDIM; ++d) {
        const float* wr = Wv + (size_t)d * DDIM;
#pragma unroll
        for (int k = 0; k < 4; ++k) {
            int c = t + k * 256;
            acc[k] = fmaf(cb[hofk[k] * DDIM + d], wr[c], acc[k]);
        }
    }
#pragma unroll
    for (int k = 0; k < 4; ++k) oattn[b * DDIM + t + k * 256] = acc[k];
}

// K7: out = LayerNorm(query + oattn @ Wo + bo) * gamma + beta
__global__ __launch_bounds__(256) void k_out(const float* __restrict__ query,
                                             const float* __restrict__ oattn,
                                             const float* __restrict__ Wo,
                                             const float* __restrict__ bo,
                                             const float* __restrict__ gamma,
                                             const float* __restrict__ beta,
                                             float* __restrict__ out) {
    int b = blockIdx.x;
    __shared__ float os[DDIM];
    __shared__ float xs[DDIM];
    __shared__ float red[8];
    for (int i = threadIdx.x; i < DDIM; i += 256) os[i] = oattn[b * DDIM + i];
    __syncthreads();
    int t = threadIdx.x;
    float acc[4];
#pragma unroll
    for (int k = 0; k < 4; ++k) acc[k] = bo[t + k * 256];
    for (int d = 0; d < DDIM; ++d) {
        float ov = os[d];
        const float* wr = Wo + (size_t)d * DDIM;
#pragma unroll
        for (int k = 0; k < 4; ++k) acc[k] = fmaf(ov, wr[t + k * 256], acc[k]);
    }
    float lsum = 0.f;
#pragma unroll
    for (int k = 0; k < 4; ++k) {
        float x = query[b * DDIM + t + k * 256] + acc[k];
        xs[t + k * 256] = x;
        lsum += x;
    }
#pragma unroll
    for (int off = 32; off > 0; off >>= 1) lsum += __shfl_xor(lsum, off, 64);
    if ((t & 63) == 0) red[t >> 6] = lsum;
    __syncthreads();
    float mu = (red[0] + red[1] + red[2] + red[3]) * (1.f / DDIM);
    float lsq = 0.f;
#pragma unroll
    for (int k = 0; k < 4; ++k) {
        float dx = xs[t + k * 256] - mu;
        lsq += dx * dx;
    }
#pragma unroll
    for (int off = 32; off > 0; off >>= 1) lsq += __shfl_xor(lsq, off, 64);
    if ((t & 63) == 0) red[4 + (t >> 6)] = lsq;
    __syncthreads();
    float var = (red[4] + red[5] + red[6] + red[7]) * (1.f / DDIM);
    float rstd = rsqrtf(var + LNEPS);
#pragma unroll
    for (int k = 0; k < 4; ++k) {
        int c = t + k * 256;
        out[b * DDIM + c] = (xs[c] - mu) * rstd * gamma[c] + beta[c];
    }
}

extern "C" void kernel_launch(void* const* d_in, const int* in_sizes, int n_in,
                              void* d_out, int out_size, void* d_ws, size_t ws_size,
                              hipStream_t stream) {
    const float* query = (const float*)d_in[0];
    const float* ctx   = (const float*)d_in[1];
    const float* dist  = (const float*)d_in[2];
    const int*   mask  = (const int*)d_in[3];
    const float* Wq = (const float*)d_in[4];
    const float* bq = (const float*)d_in[5];
    const float* Wk = (const float*)d_in[6];
    const float* bk = (const float*)d_in[7];
    const float* Wv = (const float*)d_in[8];
    const float* bv = (const float*)d_in[9];
    const float* Wo = (const float*)d_in[10];
    const float* bo = (const float*)d_in[11];
    const float* gamma = (const float*)d_in[12];
    const float* beta  = (const float*)d_in[13];
    float* out = (float*)d_out;

    int B = in_sizes[0] / DDIM;              // 32
    int N = in_sizes[1] / (B * DDIM);        // 4096

    float* ws = (float*)d_ws;
    float* q      = ws;                                   // B*D
    float* qp     = q + (size_t)B * DDIM;                 // B*H*D
    float* sb     = qp + (size_t)B * NH * DDIM;           // B*H
    float* scores = sb + (size_t)B * NH;                  // B*H*N
    float* part   = scores + (size_t)B * NH * N;          // B*4*H*D
    float* ctxa   = part + (size_t)B * 4 * NH * DDIM;     // B*H*D
    float* oattn  = ctxa + (size_t)B * NH * DDIM;         // B*D

    k_q<<<B, 256, 0, stream>>>(query, Wq, bq, q);
    k_qp<<<dim3(B, DDIM / 16), 256, 0, stream>>>(q, Wk, qp);
    k_sb<<<1, B * NH, 0, stream>>>(q, bk, sb);
    k_scores<<<dim3(B, N / 64), 256, 0, stream>>>(ctx, qp, sb, dist, mask, scores, N);
    k_softmax<<<B * NH, 256, 0, stream>>>(scores, N);
    k_wsum<<<dim3(B, 4, 4), 256, 0, stream>>>(ctx, scores, part, N);
    k_red<<<B * NH, 256, 0, stream>>>(part, ctxa);
    k_vproj<<<B, 256, 0, stream>>>(ctxa, Wv, bv, oattn);
    k_out<<<B, 256, 0, stream>>>(query, oattn, Wo, bo, gamma, beta, out);
}